// Round 5
// baseline (3325.145 us; speedup 1.0000x reference)
//
#include <hip/hip_runtime.h>
#include <stdint.h>
#include <stddef.h>

#define TOK 4096     // B*S tokens
#define HD 1024      // hidden
#define NE 8         // experts
#define TDIM 64
#define NTASK 4
#define ADIM 256     // TD*NT
#define IDIM 2048
#define IVK 1280     // H + A

typedef short bf16x8 __attribute__((ext_vector_type(8)));
typedef float f32x4 __attribute__((ext_vector_type(4)));

__device__ __forceinline__ uint16_t f2b(float f) {
  uint32_t u = __float_as_uint(f);
  u += 0x7FFFu + ((u >> 16) & 1u);
  return (uint16_t)(u >> 16);
}
__device__ __forceinline__ float b2f(uint16_t h) {
  return __uint_as_float(((uint32_t)h) << 16);
}

// ---------------- f32 -> bf16 hi/lo split (2-way, strided) ----------------
__global__ void k_convert(const float* __restrict__ src, int sld,
                          uint16_t* __restrict__ dh, uint16_t* __restrict__ dl,
                          int dld, int R, int C4) {
  int total = R * C4;
  for (int idx = blockIdx.x * blockDim.x + threadIdx.x; idx < total;
       idx += gridDim.x * blockDim.x) {
    int r = idx / C4, c = idx - r * C4;
    float4 v = *(const float4*)(src + (size_t)r * sld + (size_t)c * 4);
    float f[4] = {v.x, v.y, v.z, v.w};
    uint16_t hb[4], lb[4];
#pragma unroll
    for (int j = 0; j < 4; ++j) {
      hb[j] = f2b(f[j]);
      lb[j] = f2b(f[j] - b2f(hb[j]));
    }
    ushort4 hh, ll;
    hh.x = hb[0]; hh.y = hb[1]; hh.z = hb[2]; hh.w = hb[3];
    ll.x = lb[0]; ll.y = lb[1]; ll.z = lb[2]; ll.w = lb[3];
    *(ushort4*)(dh + (size_t)r * dld + (size_t)c * 4) = hh;
    *(ushort4*)(dl + (size_t)r * dld + (size_t)c * 4) = ll;
  }
}

// ---------------- f32 -> bf16 3-way split (strided) ----------------
__global__ void k_convert3(const float* __restrict__ src, int sld,
                           uint16_t* __restrict__ d0, uint16_t* __restrict__ d1,
                           uint16_t* __restrict__ d2, int dld, int R, int C4) {
  int total = R * C4;
  for (int idx = blockIdx.x * blockDim.x + threadIdx.x; idx < total;
       idx += gridDim.x * blockDim.x) {
    int r = idx / C4, c = idx - r * C4;
    float4 v = *(const float4*)(src + (size_t)r * sld + (size_t)c * 4);
    float f[4] = {v.x, v.y, v.z, v.w};
    uint16_t b0[4], b1[4], b2v[4];
#pragma unroll
    for (int j = 0; j < 4; ++j) {
      b0[j] = f2b(f[j]);
      float r1 = f[j] - b2f(b0[j]);
      b1[j] = f2b(r1);
      b2v[j] = f2b(r1 - b2f(b1[j]));
    }
    ushort4 u0, u1, u2;
    u0.x = b0[0]; u0.y = b0[1]; u0.z = b0[2]; u0.w = b0[3];
    u1.x = b1[0]; u1.y = b1[1]; u1.z = b1[2]; u1.w = b1[3];
    u2.x = b2v[0]; u2.y = b2v[1]; u2.z = b2v[2]; u2.w = b2v[3];
    *(ushort4*)(d0 + (size_t)r * dld + (size_t)c * 4) = u0;
    *(ushort4*)(d1 + (size_t)r * dld + (size_t)c * 4) = u1;
    *(ushort4*)(d2 + (size_t)r * dld + (size_t)c * 4) = u2;
  }
}

// ---------------- ap[e][h] = attr_emb[e] . attr_proj_w[e][h] + apb ----------------
__global__ void k_ap(const float* __restrict__ ae, const float* __restrict__ apw,
                     const float* __restrict__ apb, float* __restrict__ ap) {
  int id = blockIdx.x * blockDim.x + threadIdx.x;
  if (id >= NE * HD) return;
  int e = id >> 10;
  const float* wa = apw + (size_t)id * ADIM;
  const float* av = ae + (size_t)e * ADIM;
  float s = 0.f;
  for (int a = 0; a < ADIM; a += 4) {
    float4 w4 = *(const float4*)(wa + a);
    float4 a4 = *(const float4*)(av + a);
    s += w4.x * a4.x + w4.y * a4.y + w4.z * a4.z + w4.w * a4.w;
  }
  ap[id] = s + apb[id];
}

// ---------------- cb1[e][i] = gb1[e][i] + sum_h ap[e][h]*gw1[e][i][H+h] ----------------
__global__ void k_cb1(const float* __restrict__ gw1, const float* __restrict__ gb1,
                      const float* __restrict__ ap, float* __restrict__ cb1) {
  int id = blockIdx.x * blockDim.x + threadIdx.x;
  if (id >= NE * IDIM) return;
  int e = id >> 11;
  const float* wr = gw1 + (size_t)id * (2 * HD) + HD;
  const float* av = ap + (size_t)e * HD;
  float s = 0.f;
  for (int h = 0; h < HD; h += 4) {
    float4 w4 = *(const float4*)(wr + h);
    float4 a4 = *(const float4*)(av + h);
    s += w4.x * a4.x + w4.y * a4.y + w4.z * a4.z + w4.w * a4.w;
  }
  cb1[id] = s + gb1[id];
}

// ---------------- zero d_out ----------------
__global__ void k_zero(float* __restrict__ p, int n) {
  int i = blockIdx.x * blockDim.x + threadIdx.x;
  if (i < n) p[i] = 0.f;
}

// ---------------- GEMM (3-product, expert path): C = A @ W^T ----------------
// MODE 0: relu, write hi/lo bf16
// MODE 1: g=sigmoid(v); h = ap[n] + g*(x-ap[n]); write hi/lo bf16
// MODE 2: v + x -> f32
template <int MODE>
__global__ __launch_bounds__(256, 2) void k_gemm(
    const uint16_t* __restrict__ Ah, const uint16_t* __restrict__ Al, int lda,
    const uint16_t* __restrict__ Wh, const uint16_t* __restrict__ Wl,
    const float* __restrict__ bias, int N, int K,
    uint16_t* __restrict__ outH, uint16_t* __restrict__ outL,
    float* __restrict__ outF, int ldo,
    const float* __restrict__ xbuf, const float* __restrict__ ap) {
  __shared__ uint16_t lds[2][4][128 * 32];  // 64 KiB
  const int tid = threadIdx.x;
  const int lane = tid & 63;
  const int w = tid >> 6;
  const int row0 = blockIdx.y * 128;
  const int col0 = blockIdx.x * 128;

  const uint16_t* sA_h = Ah + (size_t)row0 * lda;
  const uint16_t* sA_l = Al + (size_t)row0 * lda;
  const uint16_t* sW_h = Wh + (size_t)col0 * K;
  const uint16_t* sW_l = Wl + (size_t)col0 * K;

  auto stage = [&](int buf, int k0) {
    const uint16_t* s0[4] = {sA_h, sA_l, sW_h, sW_l};
    const int ldt[4] = {lda, lda, K, K};
#pragma unroll
    for (int t = 0; t < 4; ++t) {
#pragma unroll
      for (int j = 0; j < 2; ++j) {
        int idx = j * 256 + tid;
        int row = idx >> 2, kc = idx & 3;
        const uint16_t* g = s0[t] + (size_t)row * ldt[t] + k0 + kc * 8;
        uint16_t* l = &lds[buf][t][(j * 256 + w * 64) * 8];  // wave-uniform base
        __builtin_amdgcn_global_load_lds(
            (const __attribute__((address_space(1))) void*)g,
            (__attribute__((address_space(3))) void*)l, 16, 0, 0);
      }
    }
  };

  f32x4 acc[4][4];
#pragma unroll
  for (int r = 0; r < 4; ++r)
#pragma unroll
    for (int c = 0; c < 4; ++c) acc[r][c] = (f32x4){0.f, 0.f, 0.f, 0.f};

  const int wm = w >> 1, wn = w & 1;
  const int arow = wm * 64 + (lane & 15);
  const int brow = wn * 64 + (lane & 15);
  const int kg = lane >> 4;

  const int KT = K >> 5;
  stage(0, 0);
  __syncthreads();
  for (int kt = 0; kt < KT; ++kt) {
    const int cur = kt & 1;
    if (kt + 1 < KT) stage(cur ^ 1, (kt + 1) * 32);
    const bf16x8* tA_h = (const bf16x8*)lds[cur][0];
    const bf16x8* tA_l = (const bf16x8*)lds[cur][1];
    const bf16x8* tW_h = (const bf16x8*)lds[cur][2];
    const bf16x8* tW_l = (const bf16x8*)lds[cur][3];
    bf16x8 fa_h[4], fa_l[4], fw_h[4], fw_l[4];
#pragma unroll
    for (int r = 0; r < 4; ++r) {
      fa_h[r] = tA_h[(arow + r * 16) * 4 + kg];
      fa_l[r] = tA_l[(arow + r * 16) * 4 + kg];
    }
#pragma unroll
    for (int c = 0; c < 4; ++c) {
      fw_h[c] = tW_h[(brow + c * 16) * 4 + kg];
      fw_l[c] = tW_l[(brow + c * 16) * 4 + kg];
    }
#pragma unroll
    for (int r = 0; r < 4; ++r)
#pragma unroll
      for (int c = 0; c < 4; ++c) {
        acc[r][c] = __builtin_amdgcn_mfma_f32_16x16x32_bf16(fa_h[r], fw_h[c], acc[r][c], 0, 0, 0);
        acc[r][c] = __builtin_amdgcn_mfma_f32_16x16x32_bf16(fa_h[r], fw_l[c], acc[r][c], 0, 0, 0);
        acc[r][c] = __builtin_amdgcn_mfma_f32_16x16x32_bf16(fa_l[r], fw_h[c], acc[r][c], 0, 0, 0);
      }
    __syncthreads();
  }

#pragma unroll
  for (int r = 0; r < 4; ++r) {
    const int mbase = row0 + wm * 64 + r * 16 + (lane >> 4) * 4;
#pragma unroll
    for (int c = 0; c < 4; ++c) {
      const int n = col0 + wn * 64 + c * 16 + (lane & 15);
      const float bv = bias[n];
#pragma unroll
      for (int i = 0; i < 4; ++i) {
        const int m = mbase + i;
        const size_t o = (size_t)m * ldo + n;
        float v = acc[r][c][i] + bv;
        if (MODE == 0) {
          v = v > 0.f ? v : 0.f;
          uint16_t hb = f2b(v);
          outH[o] = hb;
          outL[o] = f2b(v - b2f(hb));
        } else if (MODE == 1) {
          const float g = 1.f / (1.f + expf(-v));
          const float apv = ap[n];
          const float hv = apv + g * (xbuf[o] - apv);
          uint16_t hb = f2b(hv);
          outH[o] = hb;
          outL[o] = f2b(hv - b2f(hb));
        } else {
          outF[o] = v + xbuf[o];
        }
      }
    }
  }
}

// ---------------- GEMM6 (6-product 3-way split, router path) ----------------
// MODE 0: relu -> 3-way bf16 split   MODE 1: relu -> f32
template <int MODE>
__global__ __launch_bounds__(256, 1) void k_gemm6(
    const uint16_t* __restrict__ A0, const uint16_t* __restrict__ A1,
    const uint16_t* __restrict__ A2, int lda,
    const uint16_t* __restrict__ W0, const uint16_t* __restrict__ W1,
    const uint16_t* __restrict__ W2,
    const float* __restrict__ bias, int N, int K,
    uint16_t* __restrict__ o0, uint16_t* __restrict__ o1,
    uint16_t* __restrict__ o2, float* __restrict__ oF, int ldo) {
  __shared__ uint16_t lds[2][6][128 * 32];  // 96 KiB -> 1 block/CU
  const int tid = threadIdx.x;
  const int lane = tid & 63;
  const int w = tid >> 6;
  const int row0 = blockIdx.y * 128;
  const int col0 = blockIdx.x * 128;

  const uint16_t* s0[6] = {A0 + (size_t)row0 * lda, A1 + (size_t)row0 * lda,
                           A2 + (size_t)row0 * lda, W0 + (size_t)col0 * K,
                           W1 + (size_t)col0 * K,  W2 + (size_t)col0 * K};

  auto stage = [&](int buf, int k0) {
#pragma unroll
    for (int t = 0; t < 6; ++t) {
      const int ldt = (t < 3) ? lda : K;
#pragma unroll
      for (int j = 0; j < 2; ++j) {
        int idx = j * 256 + tid;
        int row = idx >> 2, kc = idx & 3;
        const uint16_t* g = s0[t] + (size_t)row * ldt + k0 + kc * 8;
        uint16_t* l = &lds[buf][t][(j * 256 + w * 64) * 8];
        __builtin_amdgcn_global_load_lds(
            (const __attribute__((address_space(1))) void*)g,
            (__attribute__((address_space(3))) void*)l, 16, 0, 0);
      }
    }
  };

  f32x4 acc[4][4];
#pragma unroll
  for (int r = 0; r < 4; ++r)
#pragma unroll
    for (int c = 0; c < 4; ++c) acc[r][c] = (f32x4){0.f, 0.f, 0.f, 0.f};

  const int wm = w >> 1, wn = w & 1;
  const int arow = wm * 64 + (lane & 15);
  const int brow = wn * 64 + (lane & 15);
  const int kg = lane >> 4;

  const int KT = K >> 5;
  stage(0, 0);
  __syncthreads();
  for (int kt = 0; kt < KT; ++kt) {
    const int cur = kt & 1;
    if (kt + 1 < KT) stage(cur ^ 1, (kt + 1) * 32);
    bf16x8 fa[3][4], fw[3][4];
#pragma unroll
    for (int s = 0; s < 3; ++s) {
      const bf16x8* tA = (const bf16x8*)lds[cur][s];
      const bf16x8* tW = (const bf16x8*)lds[cur][3 + s];
#pragma unroll
      for (int r = 0; r < 4; ++r) fa[s][r] = tA[(arow + r * 16) * 4 + kg];
#pragma unroll
      for (int c = 0; c < 4; ++c) fw[s][c] = tW[(brow + c * 16) * 4 + kg];
    }
#pragma unroll
    for (int r = 0; r < 4; ++r)
#pragma unroll
      for (int c = 0; c < 4; ++c) {
        acc[r][c] = __builtin_amdgcn_mfma_f32_16x16x32_bf16(fa[0][r], fw[0][c], acc[r][c], 0, 0, 0);
        acc[r][c] = __builtin_amdgcn_mfma_f32_16x16x32_bf16(fa[0][r], fw[1][c], acc[r][c], 0, 0, 0);
        acc[r][c] = __builtin_amdgcn_mfma_f32_16x16x32_bf16(fa[1][r], fw[0][c], acc[r][c], 0, 0, 0);
        acc[r][c] = __builtin_amdgcn_mfma_f32_16x16x32_bf16(fa[1][r], fw[1][c], acc[r][c], 0, 0, 0);
        acc[r][c] = __builtin_amdgcn_mfma_f32_16x16x32_bf16(fa[0][r], fw[2][c], acc[r][c], 0, 0, 0);
        acc[r][c] = __builtin_amdgcn_mfma_f32_16x16x32_bf16(fa[2][r], fw[0][c], acc[r][c], 0, 0, 0);
      }
    __syncthreads();
  }

#pragma unroll
  for (int r = 0; r < 4; ++r) {
    const int mbase = row0 + wm * 64 + r * 16 + (lane >> 4) * 4;
#pragma unroll
    for (int c = 0; c < 4; ++c) {
      const int n = col0 + wn * 64 + c * 16 + (lane & 15);
      const float bv = bias[n];
#pragma unroll
      for (int i = 0; i < 4; ++i) {
        const int m = mbase + i;
        const size_t o = (size_t)m * ldo + n;
        float v = acc[r][c][i] + bv;
        v = v > 0.f ? v : 0.f;
        if (MODE == 0) {
          uint16_t w0 = f2b(v);
          float r1 = v - b2f(w0);
          uint16_t w1 = f2b(r1);
          o0[o] = w0;
          o1[o] = w1;
          o2[o] = f2b(r1 - b2f(w1));
        } else {
          oF[o] = v;
        }
      }
    }
  }
}

// ---------------- logits[t][e] = h2[t] . r_w[e] + r_b[e] (h2 f32) ----------------
__global__ void k_logits(const float* __restrict__ h2, const float* __restrict__ rw,
                         const float* __restrict__ rb, float* __restrict__ logits) {
  int lane = threadIdx.x & 63, w = threadIdx.x >> 6;
  int t = blockIdx.x * 4 + w;
  float hv[16];
#pragma unroll
  for (int j = 0; j < 16; ++j) hv[j] = h2[(size_t)t * HD + j * 64 + lane];
  for (int e = 0; e < NE; ++e) {
    float s = 0.f;
#pragma unroll
    for (int j = 0; j < 16; ++j) s += hv[j] * rw[(size_t)e * HD + j * 64 + lane];
#pragma unroll
    for (int off = 32; off >= 1; off >>= 1) s += __shfl_xor(s, off, 64);
    if (lane == 0) logits[t * NE + e] = s + rb[e];
  }
}

// ---------------- softmax, attr probs, top-2 mask, per-token entropy ----------------
__global__ void k_router(const float* __restrict__ te, const float* __restrict__ rattr,
                         const float* __restrict__ logits, float* __restrict__ probs,
                         float* __restrict__ entbuf) {
  int lane = threadIdx.x & 63, w = threadIdx.x >> 6;
  int t = blockIdx.x * 4 + w;
  float ap8[NE];
#pragma unroll
  for (int e = 0; e < NE; ++e) ap8[e] = 0.f;
#pragma unroll
  for (int nt = 0; nt < NTASK; ++nt) {
    float tv = te[((size_t)t * NTASK + nt) * TDIM + lane];
    float s[NE];
#pragma unroll
    for (int e = 0; e < NE; ++e) s[e] = tv * rattr[lane * NE + e];
#pragma unroll
    for (int off = 32; off >= 1; off >>= 1)
#pragma unroll
      for (int e = 0; e < NE; ++e) s[e] += __shfl_xor(s[e], off, 64);
    float mx = s[0];
#pragma unroll
    for (int e = 1; e < NE; ++e) mx = fmaxf(mx, s[e]);
    float den = 0.f, ex[NE];
#pragma unroll
    for (int e = 0; e < NE; ++e) { ex[e] = expf(s[e] - mx); den += ex[e]; }
    float inv = 1.f / den;
#pragma unroll
    for (int e = 0; e < NE; ++e) ap8[e] += ex[e] * inv * 0.25f;
  }
  float p8[NE];
  float mx = -1e30f;
#pragma unroll
  for (int e = 0; e < NE; ++e) { p8[e] = logits[t * NE + e]; mx = fmaxf(mx, p8[e]); }
  float den = 0.f;
#pragma unroll
  for (int e = 0; e < NE; ++e) { p8[e] = expf(p8[e] - mx); den += p8[e]; }
  float inv = 1.f / den;
#pragma unroll
  for (int e = 0; e < NE; ++e) p8[e] = p8[e] * inv * ap8[e];
  int i1 = 0; float b1 = p8[0];
#pragma unroll
  for (int e = 1; e < NE; ++e) if (p8[e] > b1) { b1 = p8[e]; i1 = e; }
  int i2 = -1; float b2 = -1e30f;
#pragma unroll
  for (int e = 0; e < NE; ++e) if (e != i1 && p8[e] > b2) { b2 = p8[e]; i2 = e; }
  float ent = 0.f;
#pragma unroll
  for (int e = 0; e < NE; ++e) {
    float pv = (e == i1 || e == i2) ? p8[e] : 0.f;
    if (lane == 0) probs[t * NE + e] = pv;
    ent += pv * logf(pv + 1e-8f);
  }
  if (lane == 0) entbuf[t] = ent;
}

// ---------------- deterministic loss reduction ----------------
__global__ void k_loss(const float* __restrict__ entbuf, float* __restrict__ loss) {
  __shared__ float red[256];
  float s = 0.f;
  for (int i = threadIdx.x; i < TOK; i += 256) s += entbuf[i];
  red[threadIdx.x] = s;
  __syncthreads();
  for (int o = 128; o > 0; o >>= 1) {
    if (threadIdx.x < o) red[threadIdx.x] += red[threadIdx.x + o];
    __syncthreads();
  }
  if (threadIdx.x == 0) *loss = -red[0] / (float)TOK;
}

// ---------------- out[t] += p * layernorm(h3[t]) * g + b ----------------
__global__ void k_lnacc(const float* __restrict__ h3, const float* __restrict__ probs,
                        const float* __restrict__ g, const float* __restrict__ b,
                        float* __restrict__ out, int e) {
  int t = blockIdx.x;
  float p = probs[t * NE + e];
  if (p == 0.f) return;
  int tid = threadIdx.x, lane = tid & 63, w = tid >> 6;
  __shared__ float red[8];
  float4 v = *(const float4*)(h3 + (size_t)t * HD + tid * 4);
  float s = v.x + v.y + v.z + v.w;
  float q = v.x * v.x + v.y * v.y + v.z * v.z + v.w * v.w;
#pragma unroll
  for (int off = 32; off >= 1; off >>= 1) {
    s += __shfl_xor(s, off, 64);
    q += __shfl_xor(q, off, 64);
  }
  if (lane == 0) { red[w] = s; red[4 + w] = q; }
  __syncthreads();
  s = red[0] + red[1] + red[2] + red[3];
  q = red[4] + red[5] + red[6] + red[7];
  float mu = s * (1.f / (float)HD);
  float var = q * (1.f / (float)HD) - mu * mu;
  float rs = rsqrtf(var + 1e-5f);
  float4 gv = *(const float4*)(g + (size_t)e * HD + tid * 4);
  float4 bv = *(const float4*)(b + (size_t)e * HD + tid * 4);
  float* op = out + (size_t)t * HD + tid * 4;
  op[0] += p * ((v.x - mu) * rs * gv.x + bv.x);
  op[1] += p * ((v.y - mu) * rs * gv.y + bv.y);
  op[2] += p * ((v.z - mu) * rs * gv.z + bv.z);
  op[3] += p * ((v.w - mu) * rs * gv.w + bv.w);
}

static inline int cgrid(size_t total) {
  size_t g = (total + 255) / 256;
  return (int)(g > 4096 ? 4096 : g);
}

extern "C" void kernel_launch(void* const* d_in, const int* in_sizes, int n_in,
                              void* d_out, int out_size, void* d_ws, size_t ws_size,
                              hipStream_t stream) {
  const float* x    = (const float*)d_in[0];
  const float* te   = (const float*)d_in[1];
  const float* ae   = (const float*)d_in[2];
  const float* apw  = (const float*)d_in[3];
  const float* apb  = (const float*)d_in[4];
  const float* gw1  = (const float*)d_in[5];
  const float* gb1  = (const float*)d_in[6];
  const float* gw2  = (const float*)d_in[7];
  const float* gb2  = (const float*)d_in[8];
  const float* fw1  = (const float*)d_in[9];
  const float* fb1  = (const float*)d_in[10];
  const float* fw2  = (const float*)d_in[11];
  const float* fb2  = (const float*)d_in[12];
  const float* lng  = (const float*)d_in[13];
  const float* lnb  = (const float*)d_in[14];
  const float* rattr= (const float*)d_in[15];
  const float* rinw = (const float*)d_in[16];
  const float* rinb = (const float*)d_in[17];
  const float* rmw  = (const float*)d_in[18];
  const float* rmb  = (const float*)d_in[19];
  const float* rw   = (const float*)d_in[20];
  const float* rb   = (const float*)d_in[21];
  float* out = (float*)d_out;
  float* loss = out + (size_t)TOK * HD;

  char* p0 = (char*)d_ws;
  size_t off = 0;
  auto alloc = [&](size_t n) -> char* {
    char* r = p0 + off;
    off += (n + 255) & ~(size_t)255;
    return r;
  };

  // persistent region (iv0/iv1 double as the expert-phase 2-way split)
  uint16_t* iv0 = (uint16_t*)alloc((size_t)TOK * IVK * 2);
  uint16_t* iv1 = (uint16_t*)alloc((size_t)TOK * IVK * 2);
  float* apv    = (float*)alloc((size_t)NE * HD * 4);
  float* cb1    = (float*)alloc((size_t)NE * IDIM * 4);
  float* logits = (float*)alloc((size_t)TOK * NE * 4);
  float* probs  = (float*)alloc((size_t)TOK * NE * 4);
  float* entbuf = (float*)alloc((size_t)TOK * 4);
  size_t ubase = off;

  // router-phase view
  uint16_t* iv2 = (uint16_t*)alloc((size_t)TOK * IVK * 2);
  uint16_t* rw0 = (uint16_t*)alloc((size_t)4096 * IVK * 2);
  uint16_t* rw1 = (uint16_t*)alloc((size_t)4096 * IVK * 2);
  uint16_t* rw2 = (uint16_t*)alloc((size_t)4096 * IVK * 2);
  uint16_t* h10 = (uint16_t*)alloc((size_t)TOK * 4096 * 2);
  uint16_t* h11 = (uint16_t*)alloc((size_t)TOK * 4096 * 2);
  uint16_t* h12 = (uint16_t*)alloc((size_t)TOK * 4096 * 2);
  float* h2f    = (float*)alloc((size_t)TOK * HD * 4);
  // rm aliases rw (rw dead after router GEMM1; 3x8MB fits 3x10.5MB)
  uint16_t* rm0 = rw0;
  uint16_t* rm1 = rw1;
  uint16_t* rm2 = rw2;
  size_t router_end = off;

  // expert-phase view (overlaps router buffers; router fully done first)
  off = ubase;
  uint16_t* g1h = (uint16_t*)alloc((size_t)IDIM * HD * 2);
  uint16_t* g1l = (uint16_t*)alloc((size_t)IDIM * HD * 2);
  uint16_t* g2h = (uint16_t*)alloc((size_t)HD * IDIM * 2);
  uint16_t* g2l = (uint16_t*)alloc((size_t)HD * IDIM * 2);
  uint16_t* f1h = (uint16_t*)alloc((size_t)IDIM * HD * 2);
  uint16_t* f1l = (uint16_t*)alloc((size_t)IDIM * HD * 2);
  uint16_t* f2h = (uint16_t*)alloc((size_t)HD * IDIM * 2);
  uint16_t* f2l = (uint16_t*)alloc((size_t)HD * IDIM * 2);
  uint16_t* ghh = (uint16_t*)alloc((size_t)TOK * IDIM * 2);
  uint16_t* ghl = (uint16_t*)alloc((size_t)TOK * IDIM * 2);
  uint16_t* hbh = (uint16_t*)alloc((size_t)TOK * HD * 2);
  uint16_t* hbl = (uint16_t*)alloc((size_t)TOK * HD * 2);
  // fh aliases gh (gh dead after gate GEMM2)
  uint16_t* fhh = ghh;
  uint16_t* fhl = ghl;
  float* h3     = (float*)alloc((size_t)TOK * HD * 4);
  size_t expert_end = off;

  size_t needed = router_end > expert_end ? router_end : expert_end;
  if (ws_size < needed) return;  // cannot run safely

  // ---- phase 0: conversions + per-expert constants
  k_zero<<<dim3((TOK * HD + 1 + 255) / 256), dim3(256), 0, stream>>>(out, TOK * HD + 1);
  k_convert3<<<dim3(cgrid((size_t)TOK * 256)), dim3(256), 0, stream>>>(
      x, HD, iv0, iv1, iv2, IVK, TOK, HD / 4);
  k_convert3<<<dim3(cgrid((size_t)TOK * 64)), dim3(256), 0, stream>>>(
      te, ADIM, iv0 + HD, iv1 + HD, iv2 + HD, IVK, TOK, ADIM / 4);
  k_convert3<<<dim3(cgrid((size_t)4096 * 320)), dim3(256), 0, stream>>>(
      rinw, IVK, rw0, rw1, rw2, IVK, 4096, IVK / 4);
  k_ap<<<dim3(32), dim3(256), 0, stream>>>(ae, apw, apb, apv);
  k_cb1<<<dim3(64), dim3(256), 0, stream>>>(gw1, gb1, apv, cb1);

  // ---- phase 1: router (6-product high precision)
  k_gemm6<0><<<dim3(32, 32), dim3(256), 0, stream>>>(
      iv0, iv1, iv2, IVK, rw0, rw1, rw2, rinb, 4096, IVK,
      h10, h11, h12, nullptr, 4096);
  k_convert3<<<dim3(cgrid((size_t)HD * 1024)), dim3(256), 0, stream>>>(
      rmw, 4096, rm0, rm1, rm2, 4096, HD, 4096 / 4);
  k_gemm6<1><<<dim3(8, 32), dim3(256), 0, stream>>>(
      h10, h11, h12, 4096, rm0, rm1, rm2, rmb, HD, 4096,
      nullptr, nullptr, nullptr, h2f, HD);
  k_logits<<<dim3(TOK / 4), dim3(256), 0, stream>>>(h2f, rw, rb, logits);
  k_router<<<dim3(TOK / 4), dim3(256), 0, stream>>>(te, rattr, logits, probs, entbuf);
  k_loss<<<dim3(1), dim3(256), 0, stream>>>(entbuf, loss);

  // ---- phase 2: experts (dense; unselected contribute p=0 in LN-acc)
  for (int e = 0; e < NE; ++e) {
    k_convert<<<dim3(cgrid((size_t)IDIM * 256)), dim3(256), 0, stream>>>(
        gw1 + (size_t)e * IDIM * 2 * HD, 2 * HD, g1h, g1l, HD, IDIM, HD / 4);
    k_convert<<<dim3(cgrid((size_t)HD * 512)), dim3(256), 0, stream>>>(
        gw2 + (size_t)e * HD * IDIM, IDIM, g2h, g2l, IDIM, HD, IDIM / 4);
    k_convert<<<dim3(cgrid((size_t)IDIM * 256)), dim3(256), 0, stream>>>(
        fw1 + (size_t)e * IDIM * HD, HD, f1h, f1l, HD, IDIM, HD / 4);
    k_convert<<<dim3(cgrid((size_t)HD * 512)), dim3(256), 0, stream>>>(
        fw2 + (size_t)e * HD * IDIM, IDIM, f2h, f2l, IDIM, HD, IDIM / 4);

    k_gemm<0><<<dim3(16, 32), dim3(256), 0, stream>>>(
        iv0, iv1, IVK, g1h, g1l, cb1 + (size_t)e * IDIM, IDIM, HD,
        ghh, ghl, nullptr, IDIM, nullptr, nullptr);
    k_gemm<1><<<dim3(8, 32), dim3(256), 0, stream>>>(
        ghh, ghl, IDIM, g2h, g2l, gb2 + (size_t)e * HD, HD, IDIM,
        hbh, hbl, nullptr, HD, x, apv + (size_t)e * HD);
    k_gemm<0><<<dim3(16, 32), dim3(256), 0, stream>>>(
        hbh, hbl, HD, f1h, f1l, fb1 + (size_t)e * IDIM, IDIM, HD,
        fhh, fhl, nullptr, IDIM, nullptr, nullptr);
    k_gemm<2><<<dim3(8, 32), dim3(256), 0, stream>>>(
        fhh, fhl, IDIM, f2h, f2l, fb2 + (size_t)e * HD, HD, IDIM,
        nullptr, nullptr, h3, HD, x, nullptr);
    k_lnacc<<<dim3(TOK), dim3(256), 0, stream>>>(h3, probs, lng, lnb, out, e);
  }
}